// Round 9
// baseline (621.824 us; speedup 1.0000x reference)
//
#include <hip/hip_runtime.h>

#define B_ 8192
#define T_ 36
#define F_ 36
#define N_ELEM (B_*T_*F_)   // 10616832
// bf16 xh scratch (ushort), 16B-aligned, inside fe/fem out regions
#define XHF_OFF (N_ELEM + 4)
#define XHB_OFF (2*N_ELEM + 4)

typedef __attribute__((ext_vector_type(8))) short bf16x8;
typedef __attribute__((ext_vector_type(4))) float f32x4;

__device__ inline short f2bf(float x){
  union { float f; unsigned u; } v; v.f = x;
  unsigned r = v.u + 0x7FFFu + ((v.u >> 16) & 1u);
  return (short)(r >> 16);
}
__device__ inline float bf2f(unsigned short u){
  union { unsigned u32; float f; } v; v.u32 = ((unsigned)u) << 16; return v.f;
}
__device__ inline float sigm(float x){
  return __builtin_amdgcn_rcpf(1.f + __expf(-x));
}
__device__ inline float tanhc(float x){
  x = fminf(fmaxf(x, -15.f), 15.f);
  float e = __expf(-2.f*x);
  return (1.f - e) * __builtin_amdgcn_rcpf(1.f + e);
}

// ws layout (bytes)
#define WS_WC   0         // bf16 [512][256]: cols 0..107=W_ih, 108=bias(b_ih+b_hh), 109..127=0, 128..255=W_hh
#define WS_WH   262144    // bf16 [2][64][128]: W_hist per direction, rows 36..63 = 0
#define WS_WP   294912    // bf16 [48][128]:   W_wc padded (k 72..127 = 0)
#define WS_BIAS 307200    // f32 [512] (unused by lstm now; kept for layout stability)
#define WS_LACC 309248    // f32 [72][16]: num[t] at [t][0], den[t] at [36+t][0]

__global__ __launch_bounds__(256) void prep_kernel(
    const float* __restrict__ Wih, const float* __restrict__ Whh,
    const float* __restrict__ bih, const float* __restrict__ bhh,
    const float* __restrict__ Whist, const float* __restrict__ Wwc,
    char* __restrict__ ws)
{
  short* Wc   = (short*)(ws + WS_WC);
  short* Wh   = (short*)(ws + WS_WH);
  short* Wp   = (short*)(ws + WS_WP);
  float* bias = (float*)(ws + WS_BIAS);
  float* lacc = (float*)(ws + WS_LACC);
  int i = blockIdx.x*256 + threadIdx.x;
  if (i < 131072){
    int n = i >> 8, k = i & 255;
    float v = 0.f;
    if (k < 108) v = Wih[n*108 + k];
    else if (k == 108) v = bih[n] + bhh[n];      // bias rides the constant-1 input column
    else if (k >= 128) v = Whh[n*128 + (k - 128)];
    Wc[i] = f2bf(v);
  }
  if (i < 16384){
    int d = i >> 13, f = (i >> 7) & 63, k = i & 127;
    Wh[i] = (f < 36) ? f2bf(Whist[f*256 + d*128 + k]) : (short)0;
  }
  if (i < 6144){
    int f = i >> 7, k = i & 127;
    Wp[i] = (f < 36 && k < 72) ? f2bf(Wwc[f*72 + k]) : (short)0;
  }
  if (i < 512) bias[i] = bih[i] + bhh[i];
  if (i < 1152) lacc[i] = 0.f;
}

// Persistent LSTM, BOTH directions fused: block = 32 rows x {fwd,bwd}, 8 waves,
// grid 256 = single round, 1 block/CU. Gate weights (shared by both dirs) in
// registers; bias folded into Wc col 108 against a constant-1.0 x-column.
// Staging staggered per dir (bwd: load t%4==0/write t%4==1; fwd: load 2/write 3)
// so one rg register set serves both. xh per-step bf16 stores (R6-proven path).
__global__ __launch_bounds__(512, 2) void lstm_kernel(
  const float* __restrict__ fv, const float* __restrict__ fm, const float* __restrict__ fd,
  const float* __restrict__ bv, const float* __restrict__ bm, const float* __restrict__ bd,
  const char* __restrict__ ws, float* __restrict__ out)
{
  int b0 = blockIdx.x * 32;
  const short* Wc  = (const short*)(ws + WS_WC);
  const short* WhF = (const short*)(ws + WS_WH);
  const short* WhB = (const short*)(ws + WS_WH) + 8192;
  unsigned short* xhgF = (unsigned short*)(out + XHF_OFF);
  unsigned short* xhgB = (unsigned short*)(out + XHB_OFF);

  __shared__ short xch[32768];   // [2][4][4096]: dir, slice, swizzled [32][128] bf16
  __shared__ short hb[16384];    // [2][2][4096]: dir, buf
  __shared__ float xhs[5120];    // [2][2][1280]: dir, parity, [32][40] f32

  int tid = threadIdx.x, w = tid >> 6, l = tid & 63;
  int lr = l & 15, lg = l >> 4;
  int j = w*16 + lr;
  int emt = w & 1, ent = w >> 1;   // emit M-tile / F-tile; ent==3 idle

  {
    int* z = (int*)hb;
    #pragma unroll
    for (int i = 0; i < 16; ++i) z[tid + i*512] = 0;
    int* zx = (int*)xch;
    #pragma unroll
    for (int i = 0; i < 32; ++i) zx[tid + i*512] = 0;
  }
  __syncthreads();
  // constant-1.0 column at k=108 (never touched by write_chunk: it writes k<108 only)
  if (tid < 256) {
    int d2 = tid >> 7, sl = (tid >> 5) & 3, r = tid & 31;
    int off = ((r << 8) + (108 << 1)) ^ ((r & 7) << 4);
    *(short*)((char*)xch + d2*32768 + sl*8192 + off) = (short)0x3F80;
  }

  // gate weights -> registers (once, shared by both dirs)
  bf16x8 wreg[8][4];
  #pragma unroll
  for (int kc = 0; kc < 8; ++kc)
    #pragma unroll
    for (int g = 0; g < 4; ++g)
      wreg[kc][g] = *(const bf16x8*)(Wc + (g*128 + j)*256 + kc*32 + lg*8);
  bf16x8 whr[2][4];
  {
    int fr = (ent < 3 ? ent : 0)*16 + lr;
    #pragma unroll
    for (int kc = 0; kc < 4; ++kc) {
      whr[0][kc] = *(const bf16x8*)(WhF + fr*128 + kc*32 + lg*8);
      whr[1][kc] = *(const bf16x8*)(WhB + fr*128 + kc*32 + lg*8);
    }
  }

  float c[2][2][4];
  #pragma unroll
  for (int d2 = 0; d2 < 2; ++d2)
    #pragma unroll
    for (int a = 0; a < 2; ++a)
      #pragma unroll
      for (int b = 0; b < 4; ++b) c[d2][a][b] = 0.f;

  // staging descriptors: chunk = 4 timesteps = 3456 f32x4 items
  const float* gpF[7]; const float* gpB[7]; int tin7[7], soff7[7]; bool act7[7];
  #pragma unroll
  for (int k = 0; k < 7; ++k) {
    int i = tid + k*512;
    act7[k] = i < 3456;
    int ii = act7[k] ? i : 0;
    int a = ii / 1152, rem = ii - a*1152;
    int r = rem / 36, q = rem - r*36;
    int t_in = q / 9, fq = (q - t_in*9)*4;
    gpF[k] = (a == 0 ? fv : (a == 1 ? fm : fd)) + (size_t)(b0 + r)*1296 + q*4;
    gpB[k] = (a == 0 ? bv : (a == 1 ? bm : bd)) + (size_t)(b0 + r)*1296 + q*4;
    tin7[k] = t_in;
    soff7[k] = ((r << 8) + ((a*36 + fq) << 1)) ^ ((r & 7) << 4);
  }
  f32x4 rg[7];
  auto load_chunk = [&](bool isB, int ct) {
    #pragma unroll
    for (int k = 0; k < 7; ++k)
      if (act7[k] && ct + tin7[k] < 36)
        rg[k] = __builtin_nontemporal_load((const f32x4*)((isB ? gpB[k] : gpF[k]) + ct*36));
  };
  auto write_chunk = [&](int d2, int base) {
    #pragma unroll
    for (int k = 0; k < 7; ++k)
      if (act7[k] && base + tin7[k] < 36) {
        int sl = (base + tin7[k]) & 3;
        short4 s = { f2bf(rg[k][0]), f2bf(rg[k][1]), f2bf(rg[k][2]), f2bf(rg[k][3]) };
        *(short4*)((char*)xch + d2*32768 + sl*8192 + soff7[k]) = s;
      }
  };

  // prologue: stage steps 0..3 for both dirs
  load_chunk(false, 0); write_chunk(0, 0);
  load_chunk(true, 0);  write_chunk(1, 0);
  __syncthreads();

  int cur = 0;
  for (int t = 0; t < 36; ++t) {
    int s = t & 3, nxt = cur ^ 1, par = t & 1;

    // store previous step's xh slices (both dirs, bf16; drains at this step's barrier)
    if (t > 0) {
      int tp = t - 1, pp = tp & 1;
      for (int idx = tid; idx < 576; idx += 512) {
        int d2 = idx / 288, u = idx - d2*288;
        int r = u / 9, fq = (u - r*9)*4;
        int tout = d2 ? (35 - tp) : tp;
        f32x4 v = *(const f32x4*)&xhs[d2*2560 + pp*1280 + r*40 + fq];
        ushort4 sv = { (unsigned short)f2bf(v[0]), (unsigned short)f2bf(v[1]),
                       (unsigned short)f2bf(v[2]), (unsigned short)f2bf(v[3]) };
        *(ushort4*)((d2 ? xhgB : xhgF) + ((size_t)tout*8192 + b0 + r)*36 + fq) = sv;
      }
    }

    // staggered prefetch: bwd at t%4==0, fwd at t%4==2 (consumed 1 step later)
    if (s == 0 && t < 34) load_chunk(true,  t + 2);
    if (s == 2 && t < 32) load_chunk(false, t + 2);

    // per-dir compute (independent chains -> scheduler interleaves)
    #pragma unroll
    for (int d2 = 0; d2 < 2; ++d2) {
      const char* hcur = (const char*)hb + d2*16384 + cur*8192;

      // emit xh_t = h_t @ W_hist^T -> LDS slice (parity t&1)
      if (ent < 3) {
        f32x4 ea = {0.f, 0.f, 0.f, 0.f};
        #pragma unroll
        for (int kc = 0; kc < 4; ++kc) {
          int r = emt*16 + lr, kk = kc*32 + lg*8;
          bf16x8 af = *(bf16x8*)(hcur + (((r << 8) + (kk << 1)) ^ ((r & 7) << 4)));
          ea = __builtin_amdgcn_mfma_f32_16x16x32_bf16(af, whr[d2][kc], ea, 0, 0, 0);
        }
        int f = ent*16 + lr;
        if (f < 36) {
          #pragma unroll
          for (int reg = 0; reg < 4; ++reg)
            xhs[d2*2560 + par*1280 + (emt*16 + lg*4 + reg)*40 + f] = ea[reg];
        }
      }

      if (t < 35) {
        // gates = [x_t,1 | h_t] @ Wc^T (bias included via k=108 column)
        f32x4 acc[2][4] = {};
        const char* xsl = (const char*)xch + d2*32768 + s*8192;
        #pragma unroll
        for (int kc = 0; kc < 8; ++kc) {
          const char* ub = (kc < 4) ? xsl : hcur;
          int kk = (kc & 3)*32 + lg*8;
          bf16x8 af[2];
          #pragma unroll
          for (int mt = 0; mt < 2; ++mt) {
            int r = mt*16 + lr;
            af[mt] = *(bf16x8*)(ub + (((r << 8) + (kk << 1)) ^ ((r & 7) << 4)));
          }
          #pragma unroll
          for (int g = 0; g < 4; ++g)
            #pragma unroll
            for (int mt = 0; mt < 2; ++mt)
              acc[mt][g] = __builtin_amdgcn_mfma_f32_16x16x32_bf16(af[mt], wreg[kc][g], acc[mt][g], 0, 0, 0);
        }
        #pragma unroll
        for (int mt = 0; mt < 2; ++mt) {
          #pragma unroll
          for (int reg = 0; reg < 4; ++reg) {
            float gi = sigm(acc[mt][0][reg]);
            float gf = sigm(acc[mt][1][reg]);
            float gg = tanhc(acc[mt][2][reg]);
            float go = sigm(acc[mt][3][reg]);
            float cc = gf * c[d2][mt][reg] + gi * gg;
            c[d2][mt][reg] = cc;
            float h = go * tanhc(cc);
            int rr = mt*16 + lg*4 + reg;
            *(short*)((char*)hb + d2*16384 + nxt*8192 +
                      (((rr << 8) + (j << 1)) ^ ((rr & 7) << 4))) = f2bf(h);
          }
        }
      }
    }

    // staging commit (extra barrier): bwd at t%4==1, fwd at t%4==3
    if ((t & 1) && t < 35) {
      __syncthreads();
      if (s == 1) write_chunk(1, t + 1);
      else        write_chunk(0, t + 1);
    }
    __syncthreads();
    cur = nxt;
  }

  // final slices t=35 (parity 1), both dirs
  for (int idx = tid; idx < 576; idx += 512) {
    int d2 = idx / 288, u = idx - d2*288;
    int r = u / 9, fq = (u - r*9)*4;
    int tout = d2 ? 0 : 35;
    f32x4 v = *(const f32x4*)&xhs[d2*2560 + 1280 + r*40 + fq];
    ushort4 sv = { (unsigned short)f2bf(v[0]), (unsigned short)f2bf(v[1]),
                   (unsigned short)f2bf(v[2]), (unsigned short)f2bf(v[3]) };
    *(ushort4*)((d2 ? xhgB : xhgF) + ((size_t)tout*8192 + b0 + r)*36 + fq) = sv;
  }
}

// Finish (t-major): block = 64 consecutive b at one t. alpha via MFMA, x_c, masked-L1 partials.
__global__ __launch_bounds__(256) void finish_kernel(
  const float* __restrict__ fv, const float* __restrict__ fm, const float* __restrict__ fd,
  const float* __restrict__ bwc, const float* __restrict__ bhist,
  const char* __restrict__ ws, float* __restrict__ out)
{
  const short* Wp = (const short*)(ws + WS_WP);
  float* lacc = (float*)(ws + WS_LACC);
  float* imp = out + 1;
  const unsigned short* xhf = (const unsigned short*)(out + XHF_OFF);
  const unsigned short* xhb = (const unsigned short*)(out + XHB_OFF);
  __shared__ short u2[8192];
  __shared__ float nacc, dacc;
  int tid = threadIdx.x, w = tid >> 6, l = tid & 63;
  int lr = l & 15, lg = l >> 4;
  int t = blockIdx.x >> 7;
  int b0 = (blockIdx.x & 127) * 64;

  if (tid == 0) { nacc = 0.f; dacc = 0.f; }

  for (int idx = tid; idx < 2048; idx += 256) {
    int r = idx >> 5, q = idx & 31;
    short4 s4 = {0, 0, 0, 0};
    if (q < 9) {
      f32x4 x4 = *(const f32x4*)(fm + ((size_t)(b0 + r)*36 + t)*36 + q*4);
      s4 = make_short4(f2bf(x4[0]), f2bf(x4[1]), f2bf(x4[2]), f2bf(x4[3]));
    } else if (q < 18) {
      f32x4 x4 = *(const f32x4*)(fd + ((size_t)(b0 + r)*36 + t)*36 + (q - 9)*4);
      s4 = make_short4(f2bf(x4[0]), f2bf(x4[1]), f2bf(x4[2]), f2bf(x4[3]));
    }
    int off = ((r << 8) + ((q*4) << 1)) ^ ((r & 7) << 4);
    *(short4*)((char*)u2 + off) = s4;
  }
  __syncthreads();

  f32x4 acc[3] = {};
  #pragma unroll
  for (int kc = 0; kc < 3; ++kc) {
    int r = w*16 + lr, k = kc*32 + lg*8;
    bf16x8 af = *(bf16x8*)((char*)u2 + (((r << 8) + (k << 1)) ^ ((r & 7) << 4)));
    #pragma unroll
    for (int nt = 0; nt < 3; ++nt) {
      int f = nt*16 + lr;
      bf16x8 bfr = *(const bf16x8*)(Wp + f*128 + kc*32 + lg*8);
      acc[nt] = __builtin_amdgcn_mfma_f32_16x16x32_bf16(af, bfr, acc[nt], 0, 0, 0);
    }
  }

  #pragma unroll
  for (int reg = 0; reg < 4; ++reg) {
    int rr = w*16 + lg*4 + reg;
    size_t b = b0 + rr;
    float ns = 0.f, ds = 0.f;
    #pragma unroll
    for (int nt = 0; nt < 3; ++nt) {
      int f = nt*16 + lr;
      if (f < 36) {
        size_t gi  = (b*36 + t)*36 + f;
        size_t gi2 = ((size_t)t*8192 + b)*36 + f;
        float alpha = sigm(acc[nt][reg] + bwc[f]);
        float xhv = bf2f(xhf[gi2]) + bf2f(xhb[gi2]) + bhist[f];
        float xc = alpha*xhv + 1.f - alpha;
        imp[gi] = xc;
        float mm = fm[gi];
        ns += fabsf(fv[gi] - xc) * mm;
        ds += mm;
      }
    }
    #pragma unroll
    for (int s = 1; s < 16; s <<= 1) { ns += __shfl_xor(ns, s); ds += __shfl_xor(ds, s); }
    if (lr == 0) { atomicAdd(&nacc, ns); atomicAdd(&dacc, ds); }
  }
  __syncthreads();
  if (tid == 0) {
    atomicAdd(lacc + t*16, nacc);
    atomicAdd(lacc + (36 + t)*16, dacc);
  }
}

__global__ void loss_final_kernel(const char* __restrict__ ws, float* __restrict__ out){
  const float* lacc = (const float*)(ws + WS_LACC);
  int t = threadIdx.x;
  float v = 0.f;
  if (t < 36) v = lacc[t*16] / (lacc[(36 + t)*16] + 1e-5f);
  #pragma unroll
  for (int s = 1; s < 64; s <<= 1) v += __shfl_xor(v, s);
  if (t == 0) out[0] = 0.3f * v;
}

extern "C" void kernel_launch(void* const* d_in, const int* in_sizes, int n_in,
                              void* d_out, int out_size, void* d_ws, size_t ws_size,
                              hipStream_t stream)
{
  const float* fv    = (const float*)d_in[0];
  const float* fm    = (const float*)d_in[1];
  const float* fd    = (const float*)d_in[2];
  const float* fe    = (const float*)d_in[3];
  const float* fem   = (const float*)d_in[4];
  const float* bv    = (const float*)d_in[5];
  const float* bm    = (const float*)d_in[6];
  const float* bd    = (const float*)d_in[7];
  const float* Wih   = (const float*)d_in[8];
  const float* Whh   = (const float*)d_in[9];
  const float* bih   = (const float*)d_in[10];
  const float* bhh   = (const float*)d_in[11];
  const float* Whist = (const float*)d_in[12];
  const float* bhist = (const float*)d_in[13];
  const float* Wwc   = (const float*)d_in[14];
  const float* bwc   = (const float*)d_in[15];
  float* out = (float*)d_out;
  char* ws = (char*)d_ws;

  prep_kernel<<<512, 256, 0, stream>>>(Wih, Whh, bih, bhh, Whist, Wwc, ws);
  lstm_kernel<<<256, 512, 0, stream>>>(fv, fm, fd, bv, bm, bd, ws, out);
  finish_kernel<<<4608, 256, 0, stream>>>(fv, fm, fd, bwc, bhist, ws, out);
  loss_final_kernel<<<1, 64, 0, stream>>>(ws, out);

  hipMemcpyAsync(out + 1 + (size_t)N_ELEM, fe,  (size_t)N_ELEM*4, hipMemcpyDeviceToDevice, stream);
  hipMemcpyAsync(out + 1 + 2*(size_t)N_ELEM, fem, (size_t)N_ELEM*4, hipMemcpyDeviceToDevice, stream);
}